// Round 9
// baseline (398.499 us; speedup 1.0000x reference)
//
#include <hip/hip_runtime.h>
#include <stdint.h>

#define B_BATCH 64
#define L_SEQ 2048
#define E_DIM 1024
#define A_DIM 512

typedef __attribute__((ext_vector_type(4))) float f32x4;
typedef __attribute__((ext_vector_type(8))) short bf16x8;
typedef __attribute__((ext_vector_type(2))) unsigned int u32x2;
typedef __attribute__((ext_vector_type(4))) unsigned int u32x4;

__device__ __forceinline__ unsigned short f2bf(float f) {
  unsigned u = __float_as_uint(f);
  u = (u + 0x7fffu + ((u >> 16) & 1u)) >> 16;  // RNE
  return (unsigned short)u;
}

__device__ __forceinline__ u32x2 packbf(f32x4 v) {
  u32x2 r;
  r.x = (unsigned)f2bf(v.x) | ((unsigned)f2bf(v.y) << 16);
  r.y = (unsigned)f2bf(v.z) | ((unsigned)f2bf(v.w) << 16);
  return r;
}

// A-LDS chunk (32-k x 128 rows): row-major 64 B rows, 16B slot s of row n at s ^ ((n>>1)&3),
// slot g holds k {4g..4g+3, 16+4g..16+4g+3}  (frag layout proven R1-R7).
// BK=128 buffer = 4 chunks = 32 KB; double-buffered.
#define CHUNKB 8192
#define ABUF (4 * CHUNKB)
#define BCHUNK 32768         // ws_B bytes per 32-k chunk (512 cols x 64 B frags)
#define BCOPY (32 * BCHUNK)  // 1 MB per XCD copy

// ---------------- K0: We_w (fp32 [1024,512]) -> ws_B bf16 frag image, replicated x8 --------
__global__ void prep_we_kernel(const float* __restrict__ We, char* __restrict__ wsB) {
  int t = blockIdx.x * 256 + threadIdx.x;  // 65536 threads = 1 16B chunk each
  int lane = t & 63;
  int colblk = (t >> 6) & 31;
  int step = t >> 11;  // 0..31
  int nl = lane & 15, g = lane >> 4;
  int col = colblk * 16 + nl;
  int k0 = step * 32 + 4 * g;
  unsigned q0 = (unsigned)f2bf(We[(size_t)(k0 + 0) * A_DIM + col]) |
                ((unsigned)f2bf(We[(size_t)(k0 + 1) * A_DIM + col]) << 16);
  unsigned q1 = (unsigned)f2bf(We[(size_t)(k0 + 2) * A_DIM + col]) |
                ((unsigned)f2bf(We[(size_t)(k0 + 3) * A_DIM + col]) << 16);
  unsigned q2 = (unsigned)f2bf(We[(size_t)(k0 + 16) * A_DIM + col]) |
                ((unsigned)f2bf(We[(size_t)(k0 + 17) * A_DIM + col]) << 16);
  unsigned q3 = (unsigned)f2bf(We[(size_t)(k0 + 18) * A_DIM + col]) |
                ((unsigned)f2bf(We[(size_t)(k0 + 19) * A_DIM + col]) << 16);
  u32x4 v; v.x = q0; v.y = q1; v.z = q2; v.w = q3;
#pragma unroll
  for (int c = 0; c < 8; ++c)
    *(u32x4*)(wsB + (size_t)c * BCOPY + (size_t)t * 16) = v;
}

// ---------------- K1: dcomb[b][a] = decoder_hidden[b]·Wd_w[:,a] + Wd_b[a] + We_b[a] --------
__global__ void dec_comb_kernel(const float* __restrict__ dh, const float* __restrict__ Wd,
                                const float* __restrict__ Wdb, const float* __restrict__ Web,
                                float* __restrict__ dcomb) {
  __shared__ float sh[1024];
  const int b = blockIdx.x, tid = threadIdx.x;
  for (int i = tid; i < 1024; i += 128) sh[i] = dh[b * 1024 + i];
  __syncthreads();
  const int a = blockIdx.y * 128 + tid;
  float acc = Wdb[a] + Web[a];
#pragma unroll 4
  for (int e = 0; e < 1024; ++e) acc += sh[e] * Wd[(size_t)e * A_DIM + a];
  dcomb[b * A_DIM + a] = acc;
}

// ---------------- K2: fused score GEMM, BK=128, contiguous A-streaming ---------------------
// block: 128 rows x 512 cols, 8 waves, wave = 128x64. 8 iters of BK=128; 1 barrier/iter.
// A: per iter block reads 128 rows x 512 B CONTIGUOUS (wave-instr = 2 rows x 512 B),
//    fp32 -> reg -> bf16 -> LDS (2x32 KB buffers). B: L2 bf16 frags -> reg, depth 1.
// vmcnt ledger (instruction counts): steady vmcnt(6); iter-end vmcnt(4); tail 4,4,4,0.
__global__ __launch_bounds__(512, 2) void score_gemm_kernel(
    const float* __restrict__ enc, const char* __restrict__ wsB,
    const float* __restrict__ dcomb, const float* __restrict__ wf,
    float* __restrict__ scoreOut) {
  __shared__ __align__(16) char smem[2 * ABUF];
  __shared__ float s_score[128];

  const int tid = threadIdx.x;
  const int lane = tid & 63;
  const int w = tid >> 6;      // 0..7
  const int g = lane >> 4;
  const int nl = lane & 15;
  const int gs = g ^ ((nl >> 1) & 3);

  const int row0 = (int)blockIdx.x * 128;
  const int bb = row0 >> 11;

  if (tid < 128) s_score[tid] = 0.0f;

  const float* encA = enc + (size_t)row0 * E_DIM;
  const int anl = nl * 64 + gs * 16;  // A-frag read base within a chunk

  // A staging: thread -> row arow = tid>>5 (of each 16-row group), k-quad klq = tid&31.
  // Load pair s covers i = 2s, 2s+1: row i*16+arow (i = 0..7 -> 128 rows), 16 B at
  // k-offset t*128 + klq*4. Wave-instr = 2 rows x 512 B contiguous.
  const int arow = tid >> 5;
  const int klq = tid & 31;
  const float* asrc = encA + (size_t)arow * E_DIM + klq * 4;
  const int aw_base = (klq >> 3) * CHUNKB + arow * 64 +
                      (((tid & 3) ^ ((arow >> 1) & 3)) << 4) + ((tid >> 2) & 1) * 8;

  const char* bsrc = wsB + (size_t)(blockIdx.x & 7) * BCOPY + (w * 4) * 1024 + lane * 16;

  f32x4 acc[8][4];
#pragma unroll
  for (int rt = 0; rt < 8; ++rt)
#pragma unroll
    for (int ct = 0; ct < 4; ++ct) {
      f32x4 z = {0.f, 0.f, 0.f, 0.f};
      acc[rt][ct] = z;
    }
  f32x4 ra[2][2];
  bf16x8 bfr[2][4];

#define LOAD_P(t_, s_)                                                          \
  do {                                                                          \
    ra[(s_) & 1][0] =                                                           \
        *(const f32x4*)(asrc + (size_t)(2 * (s_)) * 16 * E_DIM + (t_) * 128);   \
    ra[(s_) & 1][1] =                                                           \
        *(const f32x4*)(asrc + (size_t)(2 * (s_) + 1) * 16 * E_DIM + (t_) * 128); \
  } while (0)

#define LOAD_B(kcg_, sl_)                                                       \
  do {                                                                          \
    _Pragma("unroll") for (int ct = 0; ct < 4; ++ct) bfr[sl_][ct] =             \
        *(const bf16x8*)(bsrc + (size_t)(kcg_)*BCHUNK + ct * 1024);             \
  } while (0)

#define WRITE_P(s_, nb_)                                                        \
  do {                                                                          \
    *(u32x2*)(smem + (nb_) + aw_base + (2 * (s_)) * 1024) = packbf(ra[(s_) & 1][0]); \
    *(u32x2*)(smem + (nb_) + aw_base + (2 * (s_) + 1) * 1024) =                 \
        packbf(ra[(s_) & 1][1]);                                                \
  } while (0)

#define MFMA_CHUNK(cb_, s_, par_)                                               \
  do {                                                                          \
    bf16x8 afr[4];                                                              \
    _Pragma("unroll") for (int rt = 0; rt < 4; ++rt) afr[rt] =                  \
        *(const bf16x8*)(smem + (cb_) + (s_)*CHUNKB + anl + rt * 1024);         \
    __builtin_amdgcn_s_setprio(1);                                              \
    _Pragma("unroll") for (int rt = 0; rt < 4; ++rt)                            \
        _Pragma("unroll") for (int ct = 0; ct < 4; ++ct) acc[rt][ct] =          \
            __builtin_amdgcn_mfma_f32_16x16x32_bf16(afr[rt], bfr[par_][ct],     \
                                                    acc[rt][ct], 0, 0, 0);      \
    __builtin_amdgcn_s_setprio(0);                                              \
    _Pragma("unroll") for (int rt = 0; rt < 4; ++rt) afr[rt] =                  \
        *(const bf16x8*)(smem + (cb_) + (s_)*CHUNKB + anl + (rt + 4) * 1024);   \
    __builtin_amdgcn_s_setprio(1);                                              \
    _Pragma("unroll") for (int rt = 0; rt < 4; ++rt)                            \
        _Pragma("unroll") for (int ct = 0; ct < 4; ++ct) acc[rt + 4][ct] =      \
            __builtin_amdgcn_mfma_f32_16x16x32_bf16(afr[rt], bfr[par_][ct],     \
                                                    acc[rt + 4][ct], 0, 0, 0);  \
    __builtin_amdgcn_s_setprio(0);                                              \
  } while (0)

  // ---- prologue: stage buf0 (iter 0's A) = pairs s=0..3 ONLY (128 rows exactly),
  // then issue B(0) so main-loop entry state is exactly [B0] = 4 outstanding.
  LOAD_P(0, 0);
  LOAD_P(0, 1);
  asm volatile("s_waitcnt vmcnt(2)" ::: "memory");  // P0 done
  WRITE_P(0, 0);
  LOAD_P(0, 2);
  asm volatile("s_waitcnt vmcnt(2)" ::: "memory");  // P1 done
  WRITE_P(1, 0);
  LOAD_P(0, 3);
  asm volatile("s_waitcnt vmcnt(2)" ::: "memory");  // P2 done
  WRITE_P(2, 0);
  asm volatile("s_waitcnt vmcnt(0)" ::: "memory");  // P3 done
  WRITE_P(3, 0);
  LOAD_B(0, 0);
  asm volatile("s_waitcnt lgkmcnt(0)" ::: "memory");
  asm volatile("s_barrier" ::: "memory");

  // ---- main: iters 0..6 compute buf(t&1), stage buf((t+1)&1)
#pragma unroll 1
  for (int t = 0; t < 7; ++t) {
    const int cb = (t & 1) * ABUF;
    const int nb = cb ^ ABUF;
    // s=0
    LOAD_P(t + 1, 0);
    LOAD_B(4 * t + 1, 1);
    asm volatile("s_waitcnt vmcnt(6)" ::: "memory");   // retires B(4t)
    MFMA_CHUNK(cb, 0, 0);
    // s=1
    LOAD_P(t + 1, 1);
    LOAD_B(4 * t + 2, 0);
    asm volatile("s_waitcnt vmcnt(6)" ::: "memory");   // retires P0, B(4t+1)
    WRITE_P(0, nb);
    MFMA_CHUNK(cb, 1, 1);
    // s=2
    LOAD_P(t + 1, 2);
    LOAD_B(4 * t + 3, 1);
    asm volatile("s_waitcnt vmcnt(6)" ::: "memory");   // retires P1, B(4t+2)
    WRITE_P(1, nb);
    MFMA_CHUNK(cb, 2, 0);
    // s=3
    LOAD_P(t + 1, 3);
    LOAD_B(4 * t + 4, 0);
    asm volatile("s_waitcnt vmcnt(4)" ::: "memory");   // retires P2, B(4t+3), P3
    WRITE_P(2, nb);
    WRITE_P(3, nb);
    MFMA_CHUNK(cb, 3, 1);                               // read cb BEFORE barrier
    asm volatile("s_waitcnt lgkmcnt(0)" ::: "memory");
    asm volatile("s_barrier" ::: "memory");
  }
  // ---- tail: iter 7, no staging
  {
    const int cb = ABUF;
    LOAD_B(29, 1);
    asm volatile("s_waitcnt vmcnt(4)" ::: "memory");   // retires B28
    MFMA_CHUNK(cb, 0, 0);
    LOAD_B(30, 0);
    asm volatile("s_waitcnt vmcnt(4)" ::: "memory");   // retires B29
    MFMA_CHUNK(cb, 1, 1);
    LOAD_B(31, 1);
    asm volatile("s_waitcnt vmcnt(4)" ::: "memory");   // retires B30
    MFMA_CHUNK(cb, 2, 0);
    asm volatile("s_waitcnt vmcnt(0)" ::: "memory");   // retires B31
    MFMA_CHUNK(cb, 3, 1);
  }

#undef LOAD_P
#undef LOAD_B
#undef WRITE_P
#undef MFMA_CHUNK

  // epilogue: h = relu(acc + db), p = h·wf, reduce over 512 cols
  float db[4], wv[4];
#pragma unroll
  for (int ct = 0; ct < 4; ++ct) {
    int a = w * 64 + ct * 16 + nl;
    db[ct] = dcomb[bb * A_DIM + a];
    wv[ct] = wf[a];
  }
#pragma unroll
  for (int rt = 0; rt < 8; ++rt) {
#pragma unroll
    for (int r = 0; r < 4; ++r) {
      float p = 0.f;
#pragma unroll
      for (int ct = 0; ct < 4; ++ct) {
        float h = acc[rt][ct][r] + db[ct];
        h = h > 0.f ? h : 0.f;
        p += h * wv[ct];
      }
      p += __shfl_xor(p, 1);
      p += __shfl_xor(p, 2);
      p += __shfl_xor(p, 4);
      p += __shfl_xor(p, 8);
      if (nl == 0) atomicAdd(&s_score[rt * 16 + g * 4 + r], p);
    }
  }
  __syncthreads();
  if (tid < 128) scoreOut[row0 + tid] = s_score[tid];
}

// ---------------- K3: softmax over L per batch, in place -----------------------------------
__global__ void softmax_kernel(float* __restrict__ attn) {
  __shared__ float red[8];
  const int b = blockIdx.x, tid = threadIdx.x;
  float* p = attn + b * L_SEQ;
  float v[8];
  float m = -1e30f;
#pragma unroll
  for (int i = 0; i < 8; ++i) {
    v[i] = p[tid + i * 256];
    m = fmaxf(m, v[i]);
  }
#pragma unroll
  for (int off = 1; off < 64; off <<= 1) m = fmaxf(m, __shfl_xor(m, off));
  const int wid = tid >> 6;
  if ((tid & 63) == 0) red[wid] = m;
  __syncthreads();
  m = fmaxf(fmaxf(red[0], red[1]), fmaxf(red[2], red[3]));
  float s = 0.f;
#pragma unroll
  for (int i = 0; i < 8; ++i) {
    v[i] = __expf(v[i] - m);
    s += v[i];
  }
#pragma unroll
  for (int off = 1; off < 64; off <<= 1) s += __shfl_xor(s, off);
  __syncthreads();
  if ((tid & 63) == 0) red[4 + wid] = s;
  __syncthreads();
  const float inv = 1.0f / (red[4] + red[5] + red[6] + red[7]);
#pragma unroll
  for (int i = 0; i < 8; ++i) p[tid + i * 256] = v[i] * inv;
}

// ---------------- K4: weighted[b][e] = sum_l alpha[b][l]*enc[b][l][e], contiguous rows -----
__global__ void weighted_kernel(const float* __restrict__ enc, const float* __restrict__ alpha,
                                float* __restrict__ outW) {
  __shared__ float sa[64];
  const int bid = blockIdx.x;  // 2048 = 64 b * 32 l-segments of 64
  const int b = bid >> 5, ls = bid & 31;
  const int tid = threadIdx.x;
  if (tid < 64) sa[tid] = alpha[b * L_SEQ + ls * 64 + tid];
  __syncthreads();
  // per il: the 256 threads read one FULL 4 KB row contiguously; thread owns e = tid*4..+3
  const float* base = enc + ((size_t)(b * L_SEQ + ls * 64)) * E_DIM;
  f32x4 acc = {0.f, 0.f, 0.f, 0.f};
#pragma unroll 8
  for (int il = 0; il < 64; ++il) {
    f32x4 v = *(const f32x4*)(base + (size_t)il * E_DIM + tid * 4);
    float al = sa[il];
    acc.x += al * v.x;
    acc.y += al * v.y;
    acc.z += al * v.z;
    acc.w += al * v.w;
  }
  float* o = outW + b * E_DIM + tid * 4;
  atomicAdd(o + 0, acc.x);
  atomicAdd(o + 1, acc.y);
  atomicAdd(o + 2, acc.z);
  atomicAdd(o + 3, acc.w);
}

extern "C" void kernel_launch(void* const* d_in, const int* in_sizes, int n_in,
                              void* d_out, int out_size, void* d_ws, size_t ws_size,
                              hipStream_t stream) {
  const float* enc = (const float*)d_in[0];
  const float* dh = (const float*)d_in[1];
  const float* WeW = (const float*)d_in[2];
  const float* WeB = (const float*)d_in[3];
  const float* WdW = (const float*)d_in[4];
  const float* WdB = (const float*)d_in[5];
  const float* WfW = (const float*)d_in[6];
  // Wf_b (d_in[7]) irrelevant: softmax is shift-invariant and attn isn't an output.

  float* out = (float*)d_out;
  float* outW = out;                      // weighted: 64*1024
  float* attn = out + B_BATCH * E_DIM;    // scores -> alpha: 64*2048

  char* wsB = (char*)d_ws;                                   // 8 copies x 1 MB
  float* dcomb = (float*)((char*)d_ws + 8 * (size_t)BCOPY);  // 64*512 fp32

  if (ws_size < 8 * (size_t)BCOPY + (size_t)B_BATCH * A_DIM * sizeof(float)) return;

  hipMemsetAsync(outW, 0, (size_t)(B_BATCH * E_DIM) * sizeof(float), stream);
  prep_we_kernel<<<256, 256, 0, stream>>>(WeW, wsB);
  dec_comb_kernel<<<dim3(B_BATCH, 4), 128, 0, stream>>>(dh, WdW, WdB, WeB, dcomb);
  score_gemm_kernel<<<(B_BATCH * L_SEQ) / 128, 512, 0, stream>>>(enc, wsB, dcomb, WfW, attn);
  softmax_kernel<<<B_BATCH, 256, 0, stream>>>(attn);
  weighted_kernel<<<B_BATCH * 32, 256, 0, stream>>>(enc, attn, outW);
}

// Round 10
// 398.061 us; speedup vs baseline: 1.0011x; 1.0011x over previous
//
#include <hip/hip_runtime.h>
#include <stdint.h>

#define B_BATCH 64
#define L_SEQ 2048
#define E_DIM 1024
#define A_DIM 512

typedef __attribute__((ext_vector_type(4))) float f32x4;
typedef __attribute__((ext_vector_type(8))) short bf16x8;
typedef __attribute__((ext_vector_type(2))) unsigned int u32x2;
typedef __attribute__((ext_vector_type(4))) unsigned int u32x4;

__device__ __forceinline__ unsigned short f2bf(float f) {
  unsigned u = __float_as_uint(f);
  u = (u + 0x7fffu + ((u >> 16) & 1u)) >> 16;  // RNE
  return (unsigned short)u;
}

__device__ __forceinline__ u32x2 packbf(f32x4 v) {
  u32x2 r;
  r.x = (unsigned)f2bf(v.x) | ((unsigned)f2bf(v.y) << 16);
  r.y = (unsigned)f2bf(v.z) | ((unsigned)f2bf(v.w) << 16);
  return r;
}

// A-LDS chunk (32-k x 128 rows): row-major 64 B rows, 16B slot s of row n at s ^ ((n>>1)&3),
// slot g holds k {4g..4g+3, 16+4g..16+4g+3}  (frag layout proven R1-R9).
#define CHUNKB 8192
#define ABUF (4 * CHUNKB)
#define BCHUNK 32768         // ws_B bytes per 32-k chunk (512 cols x 64 B frags)
#define BCOPY (32 * BCHUNK)  // 1 MB per XCD copy

// ---------------- K0: We_w (fp32 [1024,512]) -> ws_B bf16 frag image, replicated x8 --------
__global__ void prep_we_kernel(const float* __restrict__ We, char* __restrict__ wsB) {
  int t = blockIdx.x * 256 + threadIdx.x;  // 65536 threads = 1 16B chunk each
  int lane = t & 63;
  int colblk = (t >> 6) & 31;
  int step = t >> 11;  // 0..31
  int nl = lane & 15, g = lane >> 4;
  int col = colblk * 16 + nl;
  int k0 = step * 32 + 4 * g;
  unsigned q0 = (unsigned)f2bf(We[(size_t)(k0 + 0) * A_DIM + col]) |
                ((unsigned)f2bf(We[(size_t)(k0 + 1) * A_DIM + col]) << 16);
  unsigned q1 = (unsigned)f2bf(We[(size_t)(k0 + 2) * A_DIM + col]) |
                ((unsigned)f2bf(We[(size_t)(k0 + 3) * A_DIM + col]) << 16);
  unsigned q2 = (unsigned)f2bf(We[(size_t)(k0 + 16) * A_DIM + col]) |
                ((unsigned)f2bf(We[(size_t)(k0 + 17) * A_DIM + col]) << 16);
  unsigned q3 = (unsigned)f2bf(We[(size_t)(k0 + 18) * A_DIM + col]) |
                ((unsigned)f2bf(We[(size_t)(k0 + 19) * A_DIM + col]) << 16);
  u32x4 v; v.x = q0; v.y = q1; v.z = q2; v.w = q3;
#pragma unroll
  for (int c = 0; c < 8; ++c)
    *(u32x4*)(wsB + (size_t)c * BCOPY + (size_t)t * 16) = v;
}

// ---------------- K1: dcomb[b][a] = decoder_hidden[b]·Wd_w[:,a] + Wd_b[a] + We_b[a] --------
__global__ void dec_comb_kernel(const float* __restrict__ dh, const float* __restrict__ Wd,
                                const float* __restrict__ Wdb, const float* __restrict__ Web,
                                float* __restrict__ dcomb) {
  __shared__ float sh[1024];
  const int b = blockIdx.x, tid = threadIdx.x;
  for (int i = tid; i < 1024; i += 128) sh[i] = dh[b * 1024 + i];
  __syncthreads();
  const int a = blockIdx.y * 128 + tid;
  float acc = Wdb[a] + Web[a];
#pragma unroll 4
  for (int e = 0; e < 1024; ++e) acc += sh[e] * Wd[(size_t)e * A_DIM + a];
  dcomb[b * A_DIM + a] = acc;
}

// ---------------- K2: fused score GEMM, BK=128 (unchanged from R9) -------------------------
__global__ __launch_bounds__(512, 2) void score_gemm_kernel(
    const float* __restrict__ enc, const char* __restrict__ wsB,
    const float* __restrict__ dcomb, const float* __restrict__ wf,
    float* __restrict__ scoreOut) {
  __shared__ __align__(16) char smem[2 * ABUF];
  __shared__ float s_score[128];

  const int tid = threadIdx.x;
  const int lane = tid & 63;
  const int w = tid >> 6;      // 0..7
  const int g = lane >> 4;
  const int nl = lane & 15;
  const int gs = g ^ ((nl >> 1) & 3);

  const int row0 = (int)blockIdx.x * 128;
  const int bb = row0 >> 11;

  if (tid < 128) s_score[tid] = 0.0f;

  const float* encA = enc + (size_t)row0 * E_DIM;
  const int anl = nl * 64 + gs * 16;

  const int arow = tid >> 5;
  const int klq = tid & 31;
  const float* asrc = encA + (size_t)arow * E_DIM + klq * 4;
  const int aw_base = (klq >> 3) * CHUNKB + arow * 64 +
                      (((tid & 3) ^ ((arow >> 1) & 3)) << 4) + ((tid >> 2) & 1) * 8;

  const char* bsrc = wsB + (size_t)(blockIdx.x & 7) * BCOPY + (w * 4) * 1024 + lane * 16;

  f32x4 acc[8][4];
#pragma unroll
  for (int rt = 0; rt < 8; ++rt)
#pragma unroll
    for (int ct = 0; ct < 4; ++ct) {
      f32x4 z = {0.f, 0.f, 0.f, 0.f};
      acc[rt][ct] = z;
    }
  f32x4 ra[2][2];
  bf16x8 bfr[2][4];

#define LOAD_P(t_, s_)                                                          \
  do {                                                                          \
    ra[(s_) & 1][0] =                                                           \
        *(const f32x4*)(asrc + (size_t)(2 * (s_)) * 16 * E_DIM + (t_) * 128);   \
    ra[(s_) & 1][1] =                                                           \
        *(const f32x4*)(asrc + (size_t)(2 * (s_) + 1) * 16 * E_DIM + (t_) * 128); \
  } while (0)

#define LOAD_B(kcg_, sl_)                                                       \
  do {                                                                          \
    _Pragma("unroll") for (int ct = 0; ct < 4; ++ct) bfr[sl_][ct] =             \
        *(const bf16x8*)(bsrc + (size_t)(kcg_)*BCHUNK + ct * 1024);             \
  } while (0)

#define WRITE_P(s_, nb_)                                                        \
  do {                                                                          \
    *(u32x2*)(smem + (nb_) + aw_base + (2 * (s_)) * 1024) = packbf(ra[(s_) & 1][0]); \
    *(u32x2*)(smem + (nb_) + aw_base + (2 * (s_) + 1) * 1024) =                 \
        packbf(ra[(s_) & 1][1]);                                                \
  } while (0)

#define MFMA_CHUNK(cb_, s_, par_)                                               \
  do {                                                                          \
    bf16x8 afr[4];                                                              \
    _Pragma("unroll") for (int rt = 0; rt < 4; ++rt) afr[rt] =                  \
        *(const bf16x8*)(smem + (cb_) + (s_)*CHUNKB + anl + rt * 1024);         \
    __builtin_amdgcn_s_setprio(1);                                              \
    _Pragma("unroll") for (int rt = 0; rt < 4; ++rt)                            \
        _Pragma("unroll") for (int ct = 0; ct < 4; ++ct) acc[rt][ct] =          \
            __builtin_amdgcn_mfma_f32_16x16x32_bf16(afr[rt], bfr[par_][ct],     \
                                                    acc[rt][ct], 0, 0, 0);      \
    __builtin_amdgcn_s_setprio(0);                                              \
    _Pragma("unroll") for (int rt = 0; rt < 4; ++rt) afr[rt] =                  \
        *(const bf16x8*)(smem + (cb_) + (s_)*CHUNKB + anl + (rt + 4) * 1024);   \
    __builtin_amdgcn_s_setprio(1);                                              \
    _Pragma("unroll") for (int rt = 0; rt < 4; ++rt)                            \
        _Pragma("unroll") for (int ct = 0; ct < 4; ++ct) acc[rt + 4][ct] =      \
            __builtin_amdgcn_mfma_f32_16x16x32_bf16(afr[rt], bfr[par_][ct],     \
                                                    acc[rt + 4][ct], 0, 0, 0);  \
    __builtin_amdgcn_s_setprio(0);                                              \
  } while (0)

  // prologue: stage buf0 = pairs s=0..3 only; then B(0) -> entry state [B0]=4
  LOAD_P(0, 0);
  LOAD_P(0, 1);
  asm volatile("s_waitcnt vmcnt(2)" ::: "memory");
  WRITE_P(0, 0);
  LOAD_P(0, 2);
  asm volatile("s_waitcnt vmcnt(2)" ::: "memory");
  WRITE_P(1, 0);
  LOAD_P(0, 3);
  asm volatile("s_waitcnt vmcnt(2)" ::: "memory");
  WRITE_P(2, 0);
  asm volatile("s_waitcnt vmcnt(0)" ::: "memory");
  WRITE_P(3, 0);
  LOAD_B(0, 0);
  asm volatile("s_waitcnt lgkmcnt(0)" ::: "memory");
  asm volatile("s_barrier" ::: "memory");

#pragma unroll 1
  for (int t = 0; t < 7; ++t) {
    const int cb = (t & 1) * ABUF;
    const int nb = cb ^ ABUF;
    LOAD_P(t + 1, 0);
    LOAD_B(4 * t + 1, 1);
    asm volatile("s_waitcnt vmcnt(6)" ::: "memory");
    MFMA_CHUNK(cb, 0, 0);
    LOAD_P(t + 1, 1);
    LOAD_B(4 * t + 2, 0);
    asm volatile("s_waitcnt vmcnt(6)" ::: "memory");
    WRITE_P(0, nb);
    MFMA_CHUNK(cb, 1, 1);
    LOAD_P(t + 1, 2);
    LOAD_B(4 * t + 3, 1);
    asm volatile("s_waitcnt vmcnt(6)" ::: "memory");
    WRITE_P(1, nb);
    MFMA_CHUNK(cb, 2, 0);
    LOAD_P(t + 1, 3);
    LOAD_B(4 * t + 4, 0);
    asm volatile("s_waitcnt vmcnt(4)" ::: "memory");
    WRITE_P(2, nb);
    WRITE_P(3, nb);
    MFMA_CHUNK(cb, 3, 1);
    asm volatile("s_waitcnt lgkmcnt(0)" ::: "memory");
    asm volatile("s_barrier" ::: "memory");
  }
  {
    const int cb = ABUF;
    LOAD_B(29, 1);
    asm volatile("s_waitcnt vmcnt(4)" ::: "memory");
    MFMA_CHUNK(cb, 0, 0);
    LOAD_B(30, 0);
    asm volatile("s_waitcnt vmcnt(4)" ::: "memory");
    MFMA_CHUNK(cb, 1, 1);
    LOAD_B(31, 1);
    asm volatile("s_waitcnt vmcnt(4)" ::: "memory");
    MFMA_CHUNK(cb, 2, 0);
    asm volatile("s_waitcnt vmcnt(0)" ::: "memory");
    MFMA_CHUNK(cb, 3, 1);
  }

#undef LOAD_P
#undef LOAD_B
#undef WRITE_P
#undef MFMA_CHUNK

  float db[4], wv[4];
#pragma unroll
  for (int ct = 0; ct < 4; ++ct) {
    int a = w * 64 + ct * 16 + nl;
    db[ct] = dcomb[bb * A_DIM + a];
    wv[ct] = wf[a];
  }
#pragma unroll
  for (int rt = 0; rt < 8; ++rt) {
#pragma unroll
    for (int r = 0; r < 4; ++r) {
      float p = 0.f;
#pragma unroll
      for (int ct = 0; ct < 4; ++ct) {
        float h = acc[rt][ct][r] + db[ct];
        h = h > 0.f ? h : 0.f;
        p += h * wv[ct];
      }
      p += __shfl_xor(p, 1);
      p += __shfl_xor(p, 2);
      p += __shfl_xor(p, 4);
      p += __shfl_xor(p, 8);
      if (nl == 0) atomicAdd(&s_score[rt * 16 + g * 4 + r], p);
    }
  }
  __syncthreads();
  if (tid < 128) scoreOut[row0 + tid] = s_score[tid];
}

// ---------------- K3: softmax over L per batch, in place -----------------------------------
__global__ void softmax_kernel(float* __restrict__ attn) {
  __shared__ float red[8];
  const int b = blockIdx.x, tid = threadIdx.x;
  float* p = attn + b * L_SEQ;
  float v[8];
  float m = -1e30f;
#pragma unroll
  for (int i = 0; i < 8; ++i) {
    v[i] = p[tid + i * 256];
    m = fmaxf(m, v[i]);
  }
#pragma unroll
  for (int off = 1; off < 64; off <<= 1) m = fmaxf(m, __shfl_xor(m, off));
  const int wid = tid >> 6;
  if ((tid & 63) == 0) red[wid] = m;
  __syncthreads();
  m = fmaxf(fmaxf(red[0], red[1]), fmaxf(red[2], red[3]));
  float s = 0.f;
#pragma unroll
  for (int i = 0; i < 8; ++i) {
    v[i] = __expf(v[i] - m);
    s += v[i];
  }
#pragma unroll
  for (int off = 1; off < 64; off <<= 1) s += __shfl_xor(s, off);
  __syncthreads();
  if ((tid & 63) == 0) red[4 + wid] = s;
  __syncthreads();
  const float inv = 1.0f / (red[4] + red[5] + red[6] + red[7]);
#pragma unroll
  for (int i = 0; i < 8; ++i) p[tid + i * 256] = v[i] * inv;
}

// ---------------- K4a: weighted stage 1 — private partials, ZERO atomics -------------------
// block (b, ls): partial[b][ls][e] = sum_{l in segment} alpha[b][l] * enc[b][l][e].
// Reads 64 full 4 KB rows contiguously; writes its 4 KB partial contiguously.
__global__ void weighted_part_kernel(const float* __restrict__ enc,
                                     const float* __restrict__ alpha,
                                     float* __restrict__ part) {
  __shared__ float sa[64];
  const int bid = blockIdx.x;  // 2048 = 64 b * 32 l-segments of 64
  const int b = bid >> 5, ls = bid & 31;
  const int tid = threadIdx.x;
  if (tid < 64) sa[tid] = alpha[b * L_SEQ + ls * 64 + tid];
  __syncthreads();
  const float* base = enc + ((size_t)(b * L_SEQ + ls * 64)) * E_DIM;
  f32x4 acc = {0.f, 0.f, 0.f, 0.f};
#pragma unroll 8
  for (int il = 0; il < 64; ++il) {
    f32x4 v = *(const f32x4*)(base + (size_t)il * E_DIM + tid * 4);
    float al = sa[il];
    acc.x += al * v.x;
    acc.y += al * v.y;
    acc.z += al * v.z;
    acc.w += al * v.w;
  }
  *(f32x4*)(part + (size_t)bid * E_DIM + tid * 4) = acc;
}

// ---------------- K4b: weighted stage 2 — sum 32 partials per batch ------------------------
__global__ void weighted_reduce_kernel(const float* __restrict__ part,
                                       float* __restrict__ outW) {
  const int b = blockIdx.x, tid = threadIdx.x;
  const float* p = part + (size_t)b * 32 * E_DIM + tid * 4;
  f32x4 acc = {0.f, 0.f, 0.f, 0.f};
#pragma unroll 8
  for (int ls = 0; ls < 32; ++ls) {
    f32x4 v = *(const f32x4*)(p + (size_t)ls * E_DIM);
    acc.x += v.x;
    acc.y += v.y;
    acc.z += v.z;
    acc.w += v.w;
  }
  *(f32x4*)(outW + (size_t)b * E_DIM + tid * 4) = acc;
}

extern "C" void kernel_launch(void* const* d_in, const int* in_sizes, int n_in,
                              void* d_out, int out_size, void* d_ws, size_t ws_size,
                              hipStream_t stream) {
  const float* enc = (const float*)d_in[0];
  const float* dh = (const float*)d_in[1];
  const float* WeW = (const float*)d_in[2];
  const float* WeB = (const float*)d_in[3];
  const float* WdW = (const float*)d_in[4];
  const float* WdB = (const float*)d_in[5];
  const float* WfW = (const float*)d_in[6];
  // Wf_b (d_in[7]) irrelevant: softmax is shift-invariant and attn isn't an output.

  float* out = (float*)d_out;
  float* outW = out;                      // weighted: 64*1024
  float* attn = out + B_BATCH * E_DIM;    // scores -> alpha: 64*2048

  char* wsB = (char*)d_ws;                                    // 8 copies x 1 MB
  float* dcomb = (float*)((char*)d_ws + 8 * (size_t)BCOPY);   // 64*512 fp32 (128 KB)
  float* part = (float*)((char*)d_ws + 8 * (size_t)BCOPY +
                         (size_t)B_BATCH * A_DIM * sizeof(float));  // 8 MB partials

  const size_t need = 8 * (size_t)BCOPY + (size_t)B_BATCH * A_DIM * sizeof(float) +
                      (size_t)B_BATCH * 32 * E_DIM * sizeof(float);
  if (ws_size < need) return;

  prep_we_kernel<<<256, 256, 0, stream>>>(WeW, wsB);
  dec_comb_kernel<<<dim3(B_BATCH, 4), 128, 0, stream>>>(dh, WdW, WdB, WeB, dcomb);
  score_gemm_kernel<<<(B_BATCH * L_SEQ) / 128, 512, 0, stream>>>(enc, wsB, dcomb, WfW, attn);
  softmax_kernel<<<B_BATCH, 256, 0, stream>>>(attn);
  weighted_part_kernel<<<B_BATCH * 32, 256, 0, stream>>>(enc, attn, part);
  weighted_reduce_kernel<<<B_BATCH, 256, 0, stream>>>(part, outW);
}